// Round 4
// baseline (3598.036 us; speedup 1.0000x reference)
//
#include <hip/hip_runtime.h>
#include <hip/hip_bf16.h>

// Model dims
#define WLEN 2048
#define EDIM 256
#define DDIM 512
#define NLAYER 4
#define NCLS 5
#define DI 1024
#define DS 64
#define DR 32
#define DC 4
#define BB 2
#define TOK (BB*WLEN)   // 4096 tokens
#define XD (DR + 2*DS)  // 160
#define CL 128          // scan chunk length
#define NCH (WLEN/CL)   // 16 chunks per sequence

// ---------------------------------------------------------------------------
__global__ __launch_bounds__(256) void embed_k(const int* __restrict__ seq,
    const float* __restrict__ be, const float* __restrict__ pe,
    float* __restrict__ out)
{
    int idx = blockIdx.x * 256 + threadIdx.x;      // [0, TOK*EDIM)
    int e  = idx & (EDIM - 1);
    int bl = idx >> 8;
    int l  = bl & (WLEN - 1);
    int tok = seq[bl];
    out[idx] = be[tok * EDIM + e] + pe[l * EDIM + e];
}

// ---------------------------------------------------------------------------
__global__ __launch_bounds__(256) void ln_k(const float* __restrict__ x,
    const float* __restrict__ g, const float* __restrict__ b,
    float* __restrict__ out)
{
    int row  = blockIdx.x * 4 + (threadIdx.x >> 6);
    int lane = threadIdx.x & 63;
    const float* xp = x + (size_t)row * DDIM;
    float v[8];
    float s = 0.f;
#pragma unroll
    for (int i = 0; i < 8; i++) { v[i] = xp[lane + 64 * i]; s += v[i]; }
#pragma unroll
    for (int off = 32; off; off >>= 1) s += __shfl_xor(s, off, 64);
    float mu = s * (1.f / 512.f);
    float s2 = 0.f;
#pragma unroll
    for (int i = 0; i < 8; i++) { float d = v[i] - mu; s2 += d * d; }
#pragma unroll
    for (int off = 32; off; off >>= 1) s2 += __shfl_xor(s2, off, 64);
    float rs = rsqrtf(s2 * (1.f / 512.f) + 1e-5f);
#pragma unroll
    for (int i = 0; i < 8; i++) {
        int c = lane + 64 * i;
        out[(size_t)row * DDIM + c] = (v[i] - mu) * rs * g[c] + b[c];
    }
}

// ---------------------------------------------------------------------------
__global__ __launch_bounds__(256) void conv_silu_k(const float* __restrict__ xr,
    const float* __restrict__ cw, const float* __restrict__ cb,
    float* __restrict__ xs)
{
    int idx = blockIdx.x * 256 + threadIdx.x;      // [0, TOK*DI)
    int d  = idx & (DI - 1);
    int bl = idx >> 10;
    int l  = bl & (WLEN - 1);
    float acc = cb[d];
    const float* wp = cw + d * DC;
#pragma unroll
    for (int k = 0; k < DC; k++) {
        int ls = l - (DC - 1) + k;
        if (ls >= 0)
            acc = fmaf(xr[((size_t)(bl - (DC - 1) + k)) * (2 * DI) + d], wp[k], acc);
    }
    xs[idx] = acc / (1.f + __expf(-acc));          // silu
}

// ---------------------------------------------------------------------------
// Chunked selective scan.
// Phase 1: per-(b,d,chunk) local scan with h0=0. Stores z = y_loc + xs*Dp,
//          chunk-final state H, and chunk delta-sum S.
// Phase 2: per-(b,d) scan over chunks -> h0 per chunk.
// Phase 3: per-(b,d,chunk) correction y = (z + C·exp(A·cd)·h0) * silu(res),
//          written in place over delta (consumed by m_out GEMM).
#define SU 8

#define LOADG1(T0, dlt, xv, Bt, Ct)                                      \
  _Pragma("unroll")                                                      \
  for (int u = 0; u < SU; u++) {                                         \
    size_t bl = base + (size_t)(T0) + u;                                 \
    dlt[u] = delta[bl * DI + d];                                         \
    xv[u]  = xs[bl * DI + d];                                            \
    Bt[u]  = xdbl[bl * XD + DR + lane];                                  \
    Ct[u]  = xdbl[bl * XD + DR + DS + lane];                             \
  }

#define COMPG1(T0, dlt, xv, Bt, Ct)                                      \
  {                                                                      \
    float dA[SU], p[SU];                                                 \
    _Pragma("unroll")                                                    \
    for (int u = 0; u < SU; u++) dA[u] = __expf(dlt[u] * Aa);            \
    _Pragma("unroll")                                                    \
    for (int u = 0; u < SU; u++) {                                       \
      hst = fmaf(dA[u], hst, dlt[u] * xv[u] * Bt[u]);                    \
      p[u] = hst * Ct[u];                                                \
    }                                                                    \
    _Pragma("unroll")                                                    \
    for (int off = 32; off; off >>= 1) {                                 \
      _Pragma("unroll")                                                  \
      for (int u = 0; u < SU; u++) p[u] += __shfl_xor(p[u], off, 64);    \
    }                                                                    \
    _Pragma("unroll")                                                    \
    for (int u = 0; u < SU; u++) cd += dlt[u];                           \
    _Pragma("unroll")                                                    \
    for (int u = 0; u < SU; u++) {                                       \
      float z = p[u] + xv[u] * Dpd;                                      \
      if (lane == u) ybuf[(base + (size_t)(T0) + u) * DI + d] = z;       \
    }                                                                    \
  }

__global__ __launch_bounds__(256) void scan1_k(
    const float* __restrict__ delta,    // [TOK][DI]
    const float* __restrict__ xdbl,     // [TOK][XD]
    const float* __restrict__ xs,       // [TOK][DI]
    const float* __restrict__ A_log,    // [DI][DS]
    const float* __restrict__ Dp,       // [DI]
    float* __restrict__ ybuf,           // [TOK][DI]   z = y_loc + xs*Dp
    float* __restrict__ Hbuf,           // [2048*NCH][DS]
    float* __restrict__ Sbuf)           // [2048*NCH]
{
    int wid  = blockIdx.x * 4 + (threadIdx.x >> 6);  // 0..32767 == bd*NCH+c
    int lane = threadIdx.x & 63;
    int c  = wid & (NCH - 1);
    int bd = wid >> 4;                  // b*DI + d
    int d  = bd & (DI - 1);
    float Aa  = -__expf(A_log[d * DS + lane]);
    float Dpd = Dp[d];
    float hst = 0.f, cd = 0.f;
    size_t base = (size_t)(bd >> 10) * WLEN + (size_t)c * CL;

    float da[SU], xa[SU], Ba[SU], Ca[SU];
    float db[SU], xb[SU], Bb[SU], Cb[SU];

    LOADG1(0, da, xa, Ba, Ca)
    for (int t0 = 0; t0 < CL; t0 += 2 * SU) {
        LOADG1(t0 + SU, db, xb, Bb, Cb)
        COMPG1(t0, da, xa, Ba, Ca)
        if (t0 + 2 * SU < CL)
            LOADG1(t0 + 2 * SU, da, xa, Ba, Ca)
        COMPG1(t0 + SU, db, xb, Bb, Cb)
    }
    Hbuf[(size_t)wid * DS + lane] = hst;
    if (lane == 0) Sbuf[wid] = cd;
}

__global__ __launch_bounds__(256) void scan2_k(
    const float* __restrict__ Hbuf, const float* __restrict__ Sbuf,
    const float* __restrict__ A_log, float* __restrict__ h0buf)
{
    int bd   = blockIdx.x * 4 + (threadIdx.x >> 6);  // 0..2047
    int lane = threadIdx.x & 63;
    int d = bd & (DI - 1);
    float Aa = -__expf(A_log[d * DS + lane]);
    float h = 0.f;
#pragma unroll
    for (int c = 0; c < NCH; c++) {
        size_t i = (size_t)bd * NCH + c;
        h0buf[i * DS + lane] = h;
        h = __expf(Aa * Sbuf[i]) * h + Hbuf[i * DS + lane];
    }
}

#define LOADG3(T0, dlt, Ct, zz, rr)                                      \
  _Pragma("unroll")                                                      \
  for (int u = 0; u < SU; u++) {                                         \
    size_t bl = base + (size_t)(T0) + u;                                 \
    dlt[u] = delta[bl * DI + d];                                         \
    Ct[u]  = xdbl[bl * XD + DR + DS + lane];                             \
    zz[u]  = ybuf[bl * DI + d];                                          \
    rr[u]  = xr[bl * (2 * DI) + DI + d];                                 \
  }

#define COMPG3(T0, dlt, Ct, zz, rr)                                      \
  {                                                                      \
    float cds[SU], corr[SU];                                             \
    cds[0] = cd + dlt[0];                                                \
    _Pragma("unroll")                                                    \
    for (int u = 1; u < SU; u++) cds[u] = cds[u - 1] + dlt[u];           \
    cd = cds[SU - 1];                                                    \
    _Pragma("unroll")                                                    \
    for (int u = 0; u < SU; u++)                                         \
      corr[u] = Ct[u] * __expf(Aa * cds[u]) * h0l;                       \
    _Pragma("unroll")                                                    \
    for (int off = 32; off; off >>= 1) {                                 \
      _Pragma("unroll")                                                  \
      for (int u = 0; u < SU; u++)                                       \
        corr[u] += __shfl_xor(corr[u], off, 64);                         \
    }                                                                    \
    _Pragma("unroll")                                                    \
    for (int u = 0; u < SU; u++) {                                       \
      float yv = (zz[u] + corr[u]) * (rr[u] / (1.f + __expf(-rr[u])));   \
      if (lane == u) delta[(base + (size_t)(T0) + u) * DI + d] = yv;     \
    }                                                                    \
  }

__global__ __launch_bounds__(256) void scan3_k(
    float* __restrict__ delta,          // in: delta, out: final y
    const float* __restrict__ xdbl,
    const float* __restrict__ ybuf,
    const float* __restrict__ xr,
    const float* __restrict__ A_log,
    const float* __restrict__ h0buf)
{
    int wid  = blockIdx.x * 4 + (threadIdx.x >> 6);  // 0..32767 == bd*NCH+c
    int lane = threadIdx.x & 63;
    int c  = wid & (NCH - 1);
    int bd = wid >> 4;
    int d  = bd & (DI - 1);
    float Aa  = -__expf(A_log[d * DS + lane]);
    float h0l = h0buf[(size_t)wid * DS + lane];
    float cd  = 0.f;
    size_t base = (size_t)(bd >> 10) * WLEN + (size_t)c * CL;

    float da[SU], Ca[SU], za[SU], ra[SU];
    float db[SU], Cb[SU], zb[SU], rb[SU];

    LOADG3(0, da, Ca, za, ra)
    for (int t0 = 0; t0 < CL; t0 += 2 * SU) {
        LOADG3(t0 + SU, db, Cb, zb, rb)
        COMPG3(t0, da, Ca, za, ra)
        if (t0 + 2 * SU < CL)
            LOADG3(t0 + 2 * SU, da, Ca, za, ra)
        COMPG3(t0 + SU, db, Cb, zb, rb)
    }
}

// ---------------------------------------------------------------------------
// Generic f32 NT GEMM: C[M][N] = A[M][K] * W[N][K]^T (+ epilogue)
// EPI: 0 = none, 1 = +bias, 2 = relu(+bias), 3 = softplus(+bias), 4 = +resid
template<int EPI>
__global__ __launch_bounds__(256) void gemm_nt(
    const float* __restrict__ A, int lda,
    const float* __restrict__ W, int ldw,
    const float* __restrict__ bias,
    const float* __restrict__ resid, int ldr,
    float* __restrict__ C, int ldc,
    int M, int N, int K)
{
    __shared__ float As[16][64];
    __shared__ float Ws[16][64];
    const int tid = threadIdx.x;
    const int tx = tid & 15;
    const int ty = tid >> 4;
    const int bm = blockIdx.x * 64;
    const int bn = blockIdx.y * 64;
    const int lr = tid >> 2;           // 0..63: row within tile
    const int lc = (tid & 3) << 2;     // 0,4,8,12: k offset
    float acc[4][4] = {};
    for (int k0 = 0; k0 < K; k0 += 16) {
        float4 av = *(const float4*)(A + (size_t)(bm + lr) * lda + (k0 + lc));
        float4 wv = make_float4(0.f, 0.f, 0.f, 0.f);
        if (bn + lr < N)
            wv = *(const float4*)(W + (size_t)(bn + lr) * ldw + (k0 + lc));
        As[lc + 0][lr] = av.x; As[lc + 1][lr] = av.y;
        As[lc + 2][lr] = av.z; As[lc + 3][lr] = av.w;
        Ws[lc + 0][lr] = wv.x; Ws[lc + 1][lr] = wv.y;
        Ws[lc + 2][lr] = wv.z; Ws[lc + 3][lr] = wv.w;
        __syncthreads();
#pragma unroll
        for (int k = 0; k < 16; ++k) {
            float4 a = *(const float4*)&As[k][ty * 4];
            float4 w = *(const float4*)&Ws[k][tx * 4];
            float aa[4] = {a.x, a.y, a.z, a.w};
            float ww[4] = {w.x, w.y, w.z, w.w};
#pragma unroll
            for (int i = 0; i < 4; i++)
#pragma unroll
                for (int j = 0; j < 4; j++)
                    acc[i][j] = fmaf(aa[i], ww[j], acc[i][j]);
        }
        __syncthreads();
    }
#pragma unroll
    for (int i = 0; i < 4; i++) {
        int m = bm + ty * 4 + i;
#pragma unroll
        for (int j = 0; j < 4; j++) {
            int n = bn + tx * 4 + j;
            if (n >= N) continue;
            float v = acc[i][j];
            if (EPI == 1 || EPI == 2 || EPI == 3) v += bias[n];
            if (EPI == 2) v = fmaxf(v, 0.f);
            if (EPI == 3) v = fmaxf(v, 0.f) + log1pf(__expf(-fabsf(v)));
            if (EPI == 4) v += resid[(size_t)m * ldr + n];
            C[(size_t)m * ldc + n] = v;
        }
    }
}

// ---------------------------------------------------------------------------
extern "C" void kernel_launch(void* const* d_in, const int* in_sizes, int n_in,
                              void* d_out, int out_size, void* d_ws, size_t ws_size,
                              hipStream_t stream)
{
    const int*   seq        = (const int*)d_in[0];
    const float* byte_embed = (const float*)d_in[1];
    const float* pos_embed  = (const float*)d_in[2];
    const float* in_w       = (const float*)d_in[3];
    const float* in_b       = (const float*)d_in[4];
    const float* ln_g       = (const float*)d_in[5];
    const float* ln_b       = (const float*)d_in[6];
    const float* m_in_w     = (const float*)d_in[7];
    const float* conv_w     = (const float*)d_in[8];
    const float* conv_b     = (const float*)d_in[9];
    const float* xp_w       = (const float*)d_in[10];
    const float* dt_w       = (const float*)d_in[11];
    const float* dt_b       = (const float*)d_in[12];
    const float* A_log      = (const float*)d_in[13];
    const float* Dp         = (const float*)d_in[14];
    const float* m_out_w    = (const float*)d_in[15];
    const float* h1_w       = (const float*)d_in[16];
    const float* h1_b       = (const float*)d_in[17];
    const float* h2_w       = (const float*)d_in[18];
    const float* h2_b       = (const float*)d_in[19];
    const float* h3_w       = (const float*)d_in[20];
    const float* h3_b       = (const float*)d_in[21];
    float* out = (float*)d_out;

    float* ws = (float*)d_ws;
    size_t off = 0;
    float* xe    = ws + off; off += (size_t)TOK * EDIM;      // 4096x256
    float* x     = ws + off; off += (size_t)TOK * DDIM;      // residual stream
    float* h     = ws + off; off += (size_t)TOK * DDIM;      // ln out / t2
    float* xr    = ws + off; off += (size_t)TOK * 2 * DI;    // 4096x2048
    float* xs    = ws + off; off += (size_t)TOK * DI;        // 4096x1024
    float* xdbl  = ws + off; off += (size_t)TOK * XD;        // 4096x160
    float* delta = ws + off; off += (size_t)TOK * DI;        // delta -> y in place
    float* ybuf  = ws + off; off += (size_t)TOK * DI;        // chunk-local z
    float* Hbuf  = ws + off; off += (size_t)BB * DI * NCH * DS;
    float* h0buf = ws + off; off += (size_t)BB * DI * NCH * DS;
    float* Sbuf  = ws + off; off += (size_t)BB * DI * NCH;
    float* t1 = xe;   // head temp 4096x256
    float* t2 = h;    // head temp 4096x128

    // Embed + input projection
    embed_k<<<TOK * EDIM / 256, 256, 0, stream>>>(seq, byte_embed, pos_embed, xe);
    gemm_nt<1><<<dim3(TOK/64, DDIM/64), 256, 0, stream>>>(
        xe, EDIM, in_w, EDIM, in_b, nullptr, 0, x, DDIM, TOK, DDIM, EDIM);

    for (int i = 0; i < NLAYER; i++) {
        const float* lg  = ln_g  + (size_t)i * DDIM;
        const float* lb  = ln_b  + (size_t)i * DDIM;
        const float* miw = m_in_w + (size_t)i * 2 * DI * DDIM;
        const float* cw  = conv_w + (size_t)i * DI * DC;
        const float* cb  = conv_b + (size_t)i * DI;
        const float* xpw = xp_w  + (size_t)i * XD * DI;
        const float* dtw = dt_w  + (size_t)i * DI * DR;
        const float* dtb = dt_b  + (size_t)i * DI;
        const float* al  = A_log + (size_t)i * DI * DS;
        const float* dp  = Dp    + (size_t)i * DI;
        const float* mow = m_out_w + (size_t)i * DDIM * DI;

        ln_k<<<TOK/4, 256, 0, stream>>>(x, lg, lb, h);
        gemm_nt<0><<<dim3(TOK/64, 2*DI/64), 256, 0, stream>>>(
            h, DDIM, miw, DDIM, nullptr, nullptr, 0, xr, 2*DI, TOK, 2*DI, DDIM);
        conv_silu_k<<<TOK * DI / 256, 256, 0, stream>>>(xr, cw, cb, xs);
        gemm_nt<0><<<dim3(TOK/64, (XD+63)/64), 256, 0, stream>>>(
            xs, DI, xpw, DI, nullptr, nullptr, 0, xdbl, XD, TOK, XD, DI);
        gemm_nt<3><<<dim3(TOK/64, DI/64), 256, 0, stream>>>(
            xdbl, XD, dtw, DR, dtb, nullptr, 0, delta, DI, TOK, DI, DR);

        scan1_k<<<(BB*DI*NCH)/4, 256, 0, stream>>>(
            delta, xdbl, xs, al, dp, ybuf, Hbuf, Sbuf);
        scan2_k<<<(BB*DI)/4, 256, 0, stream>>>(Hbuf, Sbuf, al, h0buf);
        scan3_k<<<(BB*DI*NCH)/4, 256, 0, stream>>>(
            delta, xdbl, ybuf, xr, al, h0buf);

        gemm_nt<4><<<dim3(TOK/64, DDIM/64), 256, 0, stream>>>(
            delta, DI, mow, DI, nullptr, x, DDIM, x, DDIM, TOK, DDIM, DI);
    }

    // Head
    gemm_nt<2><<<dim3(TOK/64, 256/64), 256, 0, stream>>>(
        x, DDIM, h1_w, DDIM, h1_b, nullptr, 0, t1, 256, TOK, 256, DDIM);
    gemm_nt<2><<<dim3(TOK/64, 2), 256, 0, stream>>>(
        t1, 256, h2_w, 256, h2_b, nullptr, 0, t2, 128, TOK, 128, 256);
    gemm_nt<1><<<dim3(TOK/64, 1), 256, 0, stream>>>(
        t2, 128, h3_w, 128, h3_b, nullptr, 0, out, NCLS, TOK, NCLS, 128);
}

// Round 5
// 2377.606 us; speedup vs baseline: 1.5133x; 1.5133x over previous
//
#include <hip/hip_runtime.h>
#include <hip/hip_bf16.h>

// Model dims
#define WLEN 2048
#define EDIM 256
#define DDIM 512
#define NLAYER 4
#define NCLS 5
#define DI 1024
#define DS 64
#define DR 32
#define DC 4
#define BB 2
#define TOK (BB*WLEN)   // 4096 tokens
#define XD (DR + 2*DS)  // 160
#define CL 128          // scan chunk length
#define NCH (WLEN/CL)   // 16 chunks per sequence
#define LOG2E 1.44269504f

typedef __bf16 bf16x8 __attribute__((ext_vector_type(8)));
typedef float  f32x4  __attribute__((ext_vector_type(4)));

static __device__ __forceinline__ unsigned short f2bf(float f) {
    union { float f; unsigned u; } v; v.f = f;
    unsigned r = v.u + 0x7fffu + ((v.u >> 16) & 1u);   // RNE
    return (unsigned short)(r >> 16);
}

// ---------------------------------------------------------------------------
__global__ __launch_bounds__(256) void embed_k(const int* __restrict__ seq,
    const float* __restrict__ be, const float* __restrict__ pe,
    float* __restrict__ out)
{
    int idx = blockIdx.x * 256 + threadIdx.x;      // [0, TOK*EDIM)
    int e  = idx & (EDIM - 1);
    int bl = idx >> 8;
    int l  = bl & (WLEN - 1);
    int tok = seq[bl];
    out[idx] = be[tok * EDIM + e] + pe[l * EDIM + e];
}

// ---------------------------------------------------------------------------
// LayerNorm over 512 cols, one wave per row; emits bf16 (feeds m_in MFMA GEMM)
__global__ __launch_bounds__(256) void ln_k(const float* __restrict__ x,
    const float* __restrict__ g, const float* __restrict__ b,
    unsigned short* __restrict__ out)
{
    int row  = blockIdx.x * 4 + (threadIdx.x >> 6);
    int lane = threadIdx.x & 63;
    const float* xp = x + (size_t)row * DDIM;
    float v[8];
    float s = 0.f;
#pragma unroll
    for (int i = 0; i < 8; i++) { v[i] = xp[lane + 64 * i]; s += v[i]; }
#pragma unroll
    for (int off = 32; off; off >>= 1) s += __shfl_xor(s, off, 64);
    float mu = s * (1.f / 512.f);
    float s2 = 0.f;
#pragma unroll
    for (int i = 0; i < 8; i++) { float d = v[i] - mu; s2 += d * d; }
#pragma unroll
    for (int off = 32; off; off >>= 1) s2 += __shfl_xor(s2, off, 64);
    float rs = rsqrtf(s2 * (1.f / 512.f) + 1e-5f);
#pragma unroll
    for (int i = 0; i < 8; i++) {
        int c = lane + 64 * i;
        out[(size_t)row * DDIM + c] = f2bf((v[i] - mu) * rs * g[c] + b[c]);
    }
}

// ---------------------------------------------------------------------------
__global__ __launch_bounds__(256) void conv_silu_k(const float* __restrict__ xr,
    const float* __restrict__ cw, const float* __restrict__ cb,
    float* __restrict__ xs)
{
    int idx = blockIdx.x * 256 + threadIdx.x;      // [0, TOK*DI)
    int d  = idx & (DI - 1);
    int bl = idx >> 10;
    int l  = bl & (WLEN - 1);
    float acc = cb[d];
    const float* wp = cw + d * DC;
#pragma unroll
    for (int k = 0; k < DC; k++) {
        int ls = l - (DC - 1) + k;
        if (ls >= 0)
            acc = fmaf(xr[((size_t)(bl - (DC - 1) + k)) * (2 * DI) + d], wp[k], acc);
    }
    xs[idx] = acc / (1.f + __expf(-acc));          // silu
}

// ---------------------------------------------------------------------------
// f32 -> bf16 flat convert (weights)
__global__ __launch_bounds__(256) void f2bf_k(const float* __restrict__ in,
    unsigned short* __restrict__ out, int n)
{
    int i = blockIdx.x * 256 + threadIdx.x;
    if (i < n) out[i] = f2bf(in[i]);
}

// ---------------------------------------------------------------------------
// 64x64 tile transposes
// xr residual half [TOK][2DI] -> rT [BB*DI][WLEN]
__global__ __launch_bounds__(256) void trans_rT_k(const float* __restrict__ xr,
    float* __restrict__ rT)
{
    __shared__ float tile[64][65];
    int bt = blockIdx.x, bd = blockIdx.y, b = blockIdx.z;
    int col = threadIdx.x & 63, rr = threadIdx.x >> 6;
#pragma unroll
    for (int k = 0; k < 16; k++) {
        int i = k * 4 + rr;
        tile[i][col] = xr[((size_t)(b * WLEN + bt * 64 + i)) * (2 * DI) + DI + bd * 64 + col];
    }
    __syncthreads();
#pragma unroll
    for (int k = 0; k < 16; k++) {
        int dd = k * 4 + rr;
        rT[((size_t)(b * DI + bd * 64 + dd)) * WLEN + bt * 64 + col] = tile[col][dd];
    }
}

// xdbl C columns [TOK][XD] -> CT [BB*DS][WLEN]
__global__ __launch_bounds__(256) void trans_CT_k(const float* __restrict__ xdbl,
    float* __restrict__ CT)
{
    __shared__ float tile[64][65];
    int bt = blockIdx.x, b = blockIdx.z;
    int col = threadIdx.x & 63, rr = threadIdx.x >> 6;
#pragma unroll
    for (int k = 0; k < 16; k++) {
        int i = k * 4 + rr;
        tile[i][col] = xdbl[((size_t)(b * WLEN + bt * 64 + i)) * XD + DR + DS + col];
    }
    __syncthreads();
#pragma unroll
    for (int k = 0; k < 16; k++) {
        int ss = k * 4 + rr;
        CT[((size_t)(b * DS + ss)) * WLEN + bt * 64 + col] = tile[col][ss];
    }
}

// yT [BB*DI][WLEN] f32 -> y_bf [TOK][DI] bf16
__global__ __launch_bounds__(256) void trans_y_k(const float* __restrict__ yT,
    unsigned short* __restrict__ ybf)
{
    __shared__ float tile[64][65];
    int bt = blockIdx.x, bd = blockIdx.y, b = blockIdx.z;
    int col = threadIdx.x & 63, rr = threadIdx.x >> 6;
#pragma unroll
    for (int k = 0; k < 16; k++) {
        int i = k * 4 + rr;   // d index
        tile[i][col] = yT[((size_t)(b * DI + bd * 64 + i)) * WLEN + bt * 64 + col];
    }
    __syncthreads();
#pragma unroll
    for (int k = 0; k < 16; k++) {
        int tt = k * 4 + rr;  // t index
        ybf[((size_t)(b * WLEN + bt * 64 + tt)) * DI + bd * 64 + col] = f2bf(tile[col][tt]);
    }
}

// ---------------------------------------------------------------------------
// Chunked selective scan.
#define SU 8

#define LOADG1(T0, dlt, xv, Bt, Ct)                                      \
  _Pragma("unroll")                                                      \
  for (int u = 0; u < SU; u++) {                                         \
    size_t bl = base + (size_t)(T0) + u;                                 \
    dlt[u] = delta[bl * DI + d];                                         \
    xv[u]  = xs[bl * DI + d];                                            \
    Bt[u]  = xdbl[bl * XD + DR + lane];                                  \
    Ct[u]  = xdbl[bl * XD + DR + DS + lane];                             \
  }

#define COMPG1(T0, dlt, xv, Bt, Ct)                                      \
  {                                                                      \
    float dA[SU], p[SU], cds[SU];                                        \
    _Pragma("unroll")                                                    \
    for (int u = 0; u < SU; u++) dA[u] = __expf(dlt[u] * Aa);            \
    _Pragma("unroll")                                                    \
    for (int u = 0; u < SU; u++) {                                       \
      hst = fmaf(dA[u], hst, dlt[u] * xv[u] * Bt[u]);                    \
      p[u] = hst * Ct[u];                                                \
    }                                                                    \
    _Pragma("unroll")                                                    \
    for (int off = 32; off; off >>= 1) {                                 \
      _Pragma("unroll")                                                  \
      for (int u = 0; u < SU; u++) p[u] += __shfl_xor(p[u], off, 64);    \
    }                                                                    \
    cds[0] = cd + dlt[0];                                                \
    _Pragma("unroll")                                                    \
    for (int u = 1; u < SU; u++) cds[u] = cds[u - 1] + dlt[u];           \
    cd = cds[SU - 1];                                                    \
    _Pragma("unroll")                                                    \
    for (int u = 0; u < SU; u++) {                                       \
      float z = p[u] + xv[u] * Dpd;                                      \
      if (lane == u) {                                                   \
        zT[tbase + (size_t)(T0) + u]  = z;                               \
        cdT[tbase + (size_t)(T0) + u] = cds[u];                          \
      }                                                                  \
    }                                                                    \
  }

__global__ __launch_bounds__(256) void scan1_k(
    const float* __restrict__ delta,    // [TOK][DI]
    const float* __restrict__ xdbl,     // [TOK][XD]
    const float* __restrict__ xs,       // [TOK][DI]
    const float* __restrict__ A_log,    // [DI][DS]
    const float* __restrict__ Dp,       // [DI]
    float* __restrict__ zT,             // [BB*DI][WLEN]  z = y_loc + xs*Dp
    float* __restrict__ cdT,            // [BB*DI][WLEN]  inclusive delta prefix
    float* __restrict__ Hbuf,           // [2048*NCH][DS]
    float* __restrict__ Sbuf)           // [2048*NCH]
{
    int wid  = blockIdx.x * 4 + (threadIdx.x >> 6);  // 0..32767 == bd*NCH+c
    int lane = threadIdx.x & 63;
    int c  = wid & (NCH - 1);
    int bd = wid >> 4;                  // b*DI + d
    int d  = bd & (DI - 1);
    float Aa  = -__expf(A_log[d * DS + lane]);
    float Dpd = Dp[d];
    float hst = 0.f, cd = 0.f;
    size_t base  = (size_t)(bd >> 10) * WLEN + (size_t)c * CL;  // global token base
    size_t tbase = (size_t)bd * WLEN + (size_t)c * CL;          // transposed-plane base

    float da[SU], xa[SU], Ba[SU], Ca[SU];
    float db[SU], xb[SU], Bb[SU], Cb[SU];

    LOADG1(0, da, xa, Ba, Ca)
    for (int t0 = 0; t0 < CL; t0 += 2 * SU) {
        LOADG1(t0 + SU, db, xb, Bb, Cb)
        COMPG1(t0, da, xa, Ba, Ca)
        if (t0 + 2 * SU < CL)
            LOADG1(t0 + 2 * SU, da, xa, Ba, Ca)
        COMPG1(t0 + SU, db, xb, Bb, Cb)
    }
    Hbuf[(size_t)wid * DS + lane] = hst;
    if (lane == 0) Sbuf[wid] = cd;
}

__global__ __launch_bounds__(256) void scan2_k(
    const float* __restrict__ Hbuf, const float* __restrict__ Sbuf,
    const float* __restrict__ A_log, float* __restrict__ h0buf)
{
    int bd   = blockIdx.x * 4 + (threadIdx.x >> 6);  // 0..2047
    int lane = threadIdx.x & 63;
    int d = bd & (DI - 1);
    float Aa = -__expf(A_log[d * DS + lane]);
    float h = 0.f;
#pragma unroll
    for (int c = 0; c < NCH; c++) {
        size_t i = (size_t)bd * NCH + c;
        h0buf[i * DS + lane] = h;
        h = __expf(Aa * Sbuf[i]) * h + Hbuf[i * DS + lane];
    }
}

// scan3: lane = token. corr_t = sum_s C[t,s]*exp2(K_s*cd_t)*h0_s, then gate.
static __device__ __forceinline__ float lanef(float v, int s) {
    return __uint_as_float(__builtin_amdgcn_readlane(__float_as_uint(v), s));
}

__global__ __launch_bounds__(256) void scan3_k(
    const float* __restrict__ zT,
    const float* __restrict__ cdT,
    const float* __restrict__ rT,
    const float* __restrict__ CT,       // [BB*DS][WLEN]
    const float* __restrict__ A_log,
    const float* __restrict__ h0buf,
    float* __restrict__ yT)             // [BB*DI][WLEN]
{
    int wid  = blockIdx.x * 4 + (threadIdx.x >> 6);  // bd*NCH + c
    int lane = threadIdx.x & 63;
    int c  = wid & (NCH - 1);
    int bd = wid >> 4;
    int d  = bd & (DI - 1);
    int b  = bd >> 10;
    float Kv  = -__expf(A_log[d * DS + lane]) * LOG2E;   // lane as s
    float h0v = h0buf[(size_t)wid * DS + lane];          // lane as s
    size_t rowb = (size_t)bd * WLEN;
    const float* CTb = CT + (size_t)b * DS * WLEN;

#pragma unroll
    for (int pass = 0; pass < CL / 64; pass++) {
        int t = c * CL + pass * 64 + lane;
        float cd = cdT[rowb + t];
        float z  = zT[rowb + t];
        float r  = rT[rowb + t];
        float c0 = 0.f, c1 = 0.f, c2 = 0.f, c3 = 0.f;
#pragma unroll
        for (int s = 0; s < DS; s += 4) {
            float C0 = CTb[(size_t)(s + 0) * WLEN + t];
            float C1 = CTb[(size_t)(s + 1) * WLEN + t];
            float C2 = CTb[(size_t)(s + 2) * WLEN + t];
            float C3 = CTb[(size_t)(s + 3) * WLEN + t];
            c0 = fmaf(C0 * lanef(h0v, s + 0), exp2f(lanef(Kv, s + 0) * cd), c0);
            c1 = fmaf(C1 * lanef(h0v, s + 1), exp2f(lanef(Kv, s + 1) * cd), c1);
            c2 = fmaf(C2 * lanef(h0v, s + 2), exp2f(lanef(Kv, s + 2) * cd), c2);
            c3 = fmaf(C3 * lanef(h0v, s + 3), exp2f(lanef(Kv, s + 3) * cd), c3);
        }
        float corr = (c0 + c1) + (c2 + c3);
        float yv = (z + corr) * (r / (1.f + __expf(-r)));
        yT[rowb + t] = yv;
    }
}

// ---------------------------------------------------------------------------
// bf16 MFMA NT GEMM: C[M][N] = A[M][K] * W[N][K]^T, f32 out.
// 128x128 tile, BK=32, 4 waves (2x2 of 64x64), mfma_f32_16x16x32_bf16.
// EPI: 0 = none, 4 = +resid
template<int EPI>
__global__ __launch_bounds__(256) void gemm_bf16(
    const unsigned short* __restrict__ A,   // [M][K] bf16
    const unsigned short* __restrict__ W,   // [N][K] bf16
    const float* __restrict__ resid,
    float* __restrict__ C,
    int M, int N, int K)
{
    __shared__ unsigned short As[4 * 128 * 8];   // [kg][row][j]
    __shared__ unsigned short Bs[4 * 128 * 8];
    const int tid = threadIdx.x;
    const int bm = blockIdx.x * 128, bn = blockIdx.y * 128;
    const int l = tid & 63, w = tid >> 6;
    const int wm = (w >> 1) * 64, wn = (w & 1) * 64;
    const int srow = tid >> 1, shalf = tid & 1;
    const int kq = l >> 4, lr = l & 15;

    f32x4 acc[4][4];
#pragma unroll
    for (int i = 0; i < 4; i++)
#pragma unroll
        for (int j = 0; j < 4; j++)
            acc[i][j] = f32x4{0.f, 0.f, 0.f, 0.f};

    for (int k0 = 0; k0 < K; k0 += 32) {
        const uint4* ga = (const uint4*)(A + (size_t)(bm + srow) * K + k0 + shalf * 16);
        uint4 a0 = ga[0], a1 = ga[1];
        const uint4* gb = (const uint4*)(W + (size_t)(bn + srow) * K + k0 + shalf * 16);
        uint4 b0 = gb[0], b1 = gb[1];
        __syncthreads();
        int kg = shalf * 2;
        *(uint4*)&As[((kg    ) * 128 + srow) * 8] = a0;
        *(uint4*)&As[((kg + 1) * 128 + srow) * 8] = a1;
        *(uint4*)&Bs[((kg    ) * 128 + srow) * 8] = b0;
        *(uint4*)&Bs[((kg + 1) * 128 + srow) * 8] = b1;
        __syncthreads();
        bf16x8 av[4], bv[4];
#pragma unroll
        for (int mf = 0; mf < 4; mf++)
            av[mf] = *(const bf16x8*)&As[(kq * 128 + wm + mf * 16 + lr) * 8];
#pragma unroll
        for (int nf = 0; nf < 4; nf++)
            bv[nf] = *(const bf16x8*)&Bs[(kq * 128 + wn + nf * 16 + lr) * 8];
#pragma unroll
        for (int mf = 0; mf < 4; mf++)
#pragma unroll
            for (int nf = 0; nf < 4; nf++)
                acc[mf][nf] = __builtin_amdgcn_mfma_f32_16x16x32_bf16(
                    av[mf], bv[nf], acc[mf][nf], 0, 0, 0);
    }
#pragma unroll
    for (int mf = 0; mf < 4; mf++) {
#pragma unroll
        for (int nf = 0; nf < 4; nf++) {
#pragma unroll
            for (int r = 0; r < 4; r++) {
                int m = bm + wm + mf * 16 + kq * 4 + r;
                int n = bn + wn + nf * 16 + lr;
                float v = acc[mf][nf][r];
                if (EPI == 4) v += resid[(size_t)m * N + n];
                C[(size_t)m * N + n] = v;
            }
        }
    }
}

// ---------------------------------------------------------------------------
// Generic f32 NT GEMM (small GEMMs): C = A*W^T (+ epilogue)
// EPI: 0 none, 1 +bias, 2 relu(+bias), 3 softplus(+bias)
template<int EPI>
__global__ __launch_bounds__(256) void gemm_nt(
    const float* __restrict__ A, int lda,
    const float* __restrict__ W, int ldw,
    const float* __restrict__ bias,
    float* __restrict__ C, int ldc,
    int M, int N, int K)
{
    __shared__ float As[16][64];
    __shared__ float Ws[16][64];
    const int tid = threadIdx.x;
    const int tx = tid & 15;
    const int ty = tid >> 4;
    const int bm = blockIdx.x * 64;
    const int bn = blockIdx.y * 64;
    const int lr = tid >> 2;
    const int lc = (tid & 3) << 2;
    float acc[4][4] = {};
    for (int k0 = 0; k0 < K; k0 += 16) {
        float4 av = *(const float4*)(A + (size_t)(bm + lr) * lda + (k0 + lc));
        float4 wv = make_float4(0.f, 0.f, 0.f, 0.f);
        if (bn + lr < N)
            wv = *(const float4*)(W + (size_t)(bn + lr) * ldw + (k0 + lc));
        As[lc + 0][lr] = av.x; As[lc + 1][lr] = av.y;
        As[lc + 2][lr] = av.z; As[lc + 3][lr] = av.w;
        Ws[lc + 0][lr] = wv.x; Ws[lc + 1][lr] = wv.y;
        Ws[lc + 2][lr] = wv.z; Ws[lc + 3][lr] = wv.w;
        __syncthreads();
#pragma unroll
        for (int k = 0; k < 16; ++k) {
            float4 a = *(const float4*)&As[k][ty * 4];
            float4 w = *(const float4*)&Ws[k][tx * 4];
            float aa[4] = {a.x, a.y, a.z, a.w};
            float ww[4] = {w.x, w.y, w.z, w.w};
#pragma unroll
            for (int i = 0; i < 4; i++)
#pragma unroll
                for (int j = 0; j < 4; j++)
                    acc[i][j] = fmaf(aa[i], ww[j], acc[i][j]);
        }
        __syncthreads();
    }
#pragma unroll
    for (int i = 0; i < 4; i++) {
        int m = bm + ty * 4 + i;
#pragma unroll
        for (int j = 0; j < 4; j++) {
            int n = bn + tx * 4 + j;
            if (n >= N) continue;
            float v = acc[i][j];
            if (EPI == 1 || EPI == 2 || EPI == 3) v += bias[n];
            if (EPI == 2) v = fmaxf(v, 0.f);
            if (EPI == 3) v = fmaxf(v, 0.f) + log1pf(__expf(-fabsf(v)));
            C[(size_t)m * ldc + n] = v;
        }
    }
}

// ---------------------------------------------------------------------------
extern "C" void kernel_launch(void* const* d_in, const int* in_sizes, int n_in,
                              void* d_out, int out_size, void* d_ws, size_t ws_size,
                              hipStream_t stream)
{
    const int*   seq        = (const int*)d_in[0];
    const float* byte_embed = (const float*)d_in[1];
    const float* pos_embed  = (const float*)d_in[2];
    const float* in_w       = (const float*)d_in[3];
    const float* in_b       = (const float*)d_in[4];
    const float* ln_g       = (const float*)d_in[5];
    const float* ln_b       = (const float*)d_in[6];
    const float* m_in_w     = (const float*)d_in[7];
    const float* conv_w     = (const float*)d_in[8];
    const float* conv_b     = (const float*)d_in[9];
    const float* xp_w       = (const float*)d_in[10];
    const float* dt_w       = (const float*)d_in[11];
    const float* dt_b       = (const float*)d_in[12];
    const float* A_log      = (const float*)d_in[13];
    const float* Dp         = (const float*)d_in[14];
    const float* m_out_w    = (const float*)d_in[15];
    const float* h1_w       = (const float*)d_in[16];
    const float* h1_b       = (const float*)d_in[17];
    const float* h2_w       = (const float*)d_in[18];
    const float* h2_b       = (const float*)d_in[19];
    const float* h3_w       = (const float*)d_in[20];
    const float* h3_b       = (const float*)d_in[21];
    float* out = (float*)d_out;

    float* ws = (float*)d_ws;
    size_t off = 0;
    float* xe    = ws + off; off += (size_t)TOK * EDIM;        // 4 MB
    float* x     = ws + off; off += (size_t)TOK * DDIM;        // residual stream
    float* xr    = ws + off; off += (size_t)TOK * 2 * DI;      // 32 MB
    float* xs    = ws + off; off += (size_t)TOK * DI;          // 16 MB
    float* xdbl  = ws + off; off += (size_t)TOK * XD;
    float* delta = ws + off; off += (size_t)TOK * DI;          // also yT (aliased)
    float* zT    = ws + off; off += (size_t)BB * DI * WLEN;
    float* cdT   = ws + off; off += (size_t)BB * DI * WLEN;
    float* rT    = ws + off; off += (size_t)BB * DI * WLEN;
    float* CT    = ws + off; off += (size_t)BB * DS * WLEN;
    float* Hbuf  = ws + off; off += (size_t)BB * DI * NCH * DS;
    float* h0buf = ws + off; off += (size_t)BB * DI * NCH * DS;
    float* Sbuf  = ws + off; off += (size_t)BB * DI * NCH;
    unsigned short* h_bf  = (unsigned short*)(ws + off); off += (size_t)TOK * DDIM / 2;
    unsigned short* y_bf  = (unsigned short*)(ws + off); off += (size_t)TOK * DI / 2;
    unsigned short* wmi_bf = (unsigned short*)(ws + off); off += (size_t)NLAYER * 2 * DI * DDIM / 2;
    unsigned short* wmo_bf = (unsigned short*)(ws + off); off += (size_t)NLAYER * DDIM * DI / 2;
    float* yT = delta;            // scan3 output aliases delta (dead after scan1)
    float* t1 = xe;               // head temps
    float* t2 = (float*)h_bf;

    // Weight conversions (every call; harness re-poisons ws)
    {
        int n1 = NLAYER * 2 * DI * DDIM;
        f2bf_k<<<(n1 + 255) / 256, 256, 0, stream>>>(m_in_w, wmi_bf, n1);
        int n2 = NLAYER * DDIM * DI;
        f2bf_k<<<(n2 + 255) / 256, 256, 0, stream>>>(m_out_w, wmo_bf, n2);
    }

    // Embed + input projection (f32)
    embed_k<<<TOK * EDIM / 256, 256, 0, stream>>>(seq, byte_embed, pos_embed, xe);
    gemm_nt<1><<<dim3(TOK/64, DDIM/64), 256, 0, stream>>>(
        xe, EDIM, in_w, EDIM, in_b, x, DDIM, TOK, DDIM, EDIM);

    for (int i = 0; i < NLAYER; i++) {
        const float* lg  = ln_g  + (size_t)i * DDIM;
        const float* lb  = ln_b  + (size_t)i * DDIM;
        const unsigned short* miw = wmi_bf + (size_t)i * 2 * DI * DDIM;
        const float* cw  = conv_w + (size_t)i * DI * DC;
        const float* cb  = conv_b + (size_t)i * DI;
        const float* xpw = xp_w  + (size_t)i * XD * DI;
        const float* dtw = dt_w  + (size_t)i * DI * DR;
        const float* dtb = dt_b  + (size_t)i * DI;
        const float* al  = A_log + (size_t)i * DI * DS;
        const float* dp  = Dp    + (size_t)i * DI;
        const unsigned short* mow = wmo_bf + (size_t)i * DDIM * DI;

        ln_k<<<TOK/4, 256, 0, stream>>>(x, lg, lb, h_bf);
        gemm_bf16<0><<<dim3(TOK/128, 2*DI/128), 256, 0, stream>>>(
            h_bf, miw, nullptr, xr, TOK, 2*DI, DDIM);
        trans_rT_k<<<dim3(WLEN/64, DI/64, BB), 256, 0, stream>>>(xr, rT);
        conv_silu_k<<<TOK * DI / 256, 256, 0, stream>>>(xr, cw, cb, xs);
        gemm_nt<0><<<dim3(TOK/64, (XD+63)/64), 256, 0, stream>>>(
            xs, DI, xpw, DI, nullptr, xdbl, XD, TOK, XD, DI);
        trans_CT_k<<<dim3(WLEN/64, 1, BB), 256, 0, stream>>>(xdbl, CT);
        gemm_nt<3><<<dim3(TOK/64, DI/64), 256, 0, stream>>>(
            xdbl, XD, dtw, DR, dtb, delta, DI, TOK, DI, DR);

        scan1_k<<<(BB*DI*NCH)/4, 256, 0, stream>>>(
            delta, xdbl, xs, al, dp, zT, cdT, Hbuf, Sbuf);
        scan2_k<<<(BB*DI)/4, 256, 0, stream>>>(Hbuf, Sbuf, al, h0buf);
        scan3_k<<<(BB*DI*NCH)/4, 256, 0, stream>>>(
            zT, cdT, rT, CT, al, h0buf, yT);
        trans_y_k<<<dim3(WLEN/64, DI/64, BB), 256, 0, stream>>>(yT, y_bf);

        gemm_bf16<4><<<dim3(TOK/128, DDIM/128), 256, 0, stream>>>(
            y_bf, mow, x, x, TOK, DDIM, DI);
    }

    // Head (f32)
    gemm_nt<2><<<dim3(TOK/64, 256/64), 256, 0, stream>>>(
        x, DDIM, h1_w, DDIM, h1_b, t1, 256, TOK, 256, DDIM);
    gemm_nt<2><<<dim3(TOK/64, 2), 256, 0, stream>>>(
        t1, 256, h2_w, 256, h2_b, t2, 128, TOK, 128, 256);
    gemm_nt<1><<<dim3(TOK/64, 1), 256, 0, stream>>>(
        t2, 128, h3_w, 128, h3_b, out, NCLS, TOK, NCLS, 128);
}

// Round 6
// 1934.125 us; speedup vs baseline: 1.8603x; 1.2293x over previous
//
#include <hip/hip_runtime.h>
#include <hip/hip_bf16.h>

// Model dims
#define WLEN 2048
#define EDIM 256
#define DDIM 512
#define NLAYER 4
#define NCLS 5
#define DI 1024
#define DS 64
#define DR 32
#define DC 4
#define BB 2
#define TOK (BB*WLEN)   // 4096 tokens
#define XD (DR + 2*DS)  // 160
#define CL 128          // scan chunk length
#define NCH (WLEN/CL)   // 16 chunks per sequence
#define LOG2E 1.44269504f

typedef __bf16 bf16x8 __attribute__((ext_vector_type(8)));
typedef float  f32x4  __attribute__((ext_vector_type(4)));

static __device__ __forceinline__ unsigned short f2bf(float f) {
    union { float f; unsigned u; } v; v.f = f;
    unsigned r = v.u + 0x7fffu + ((v.u >> 16) & 1u);   // RNE
    return (unsigned short)(r >> 16);
}

// ---------------------------------------------------------------------------
__global__ __launch_bounds__(256) void embed_k(const int* __restrict__ seq,
    const float* __restrict__ be, const float* __restrict__ pe,
    float* __restrict__ out)
{
    int idx = blockIdx.x * 256 + threadIdx.x;      // [0, TOK*EDIM)
    int e  = idx & (EDIM - 1);
    int bl = idx >> 8;
    int l  = bl & (WLEN - 1);
    int tok = seq[bl];
    out[idx] = be[tok * EDIM + e] + pe[l * EDIM + e];
}

// ---------------------------------------------------------------------------
// LayerNorm over 512 cols, one wave per row; emits bf16 (feeds m_in MFMA GEMM)
__global__ __launch_bounds__(256) void ln_k(const float* __restrict__ x,
    const float* __restrict__ g, const float* __restrict__ b,
    unsigned short* __restrict__ out)
{
    int row  = blockIdx.x * 4 + (threadIdx.x >> 6);
    int lane = threadIdx.x & 63;
    const float* xp = x + (size_t)row * DDIM;
    float v[8];
    float s = 0.f;
#pragma unroll
    for (int i = 0; i < 8; i++) { v[i] = xp[lane + 64 * i]; s += v[i]; }
#pragma unroll
    for (int off = 32; off; off >>= 1) s += __shfl_xor(s, off, 64);
    float mu = s * (1.f / 512.f);
    float s2 = 0.f;
#pragma unroll
    for (int i = 0; i < 8; i++) { float d = v[i] - mu; s2 += d * d; }
#pragma unroll
    for (int off = 32; off; off >>= 1) s2 += __shfl_xor(s2, off, 64);
    float rs = rsqrtf(s2 * (1.f / 512.f) + 1e-5f);
#pragma unroll
    for (int i = 0; i < 8; i++) {
        int c = lane + 64 * i;
        out[(size_t)row * DDIM + c] = f2bf((v[i] - mu) * rs * g[c] + b[c]);
    }
}

// ---------------------------------------------------------------------------
__global__ __launch_bounds__(256) void conv_silu_k(const float* __restrict__ xr,
    const float* __restrict__ cw, const float* __restrict__ cb,
    float* __restrict__ xs)
{
    int idx = blockIdx.x * 256 + threadIdx.x;      // [0, TOK*DI)
    int d  = idx & (DI - 1);
    int bl = idx >> 10;
    int l  = bl & (WLEN - 1);
    float acc = cb[d];
    const float* wp = cw + d * DC;
#pragma unroll
    for (int k = 0; k < DC; k++) {
        int ls = l - (DC - 1) + k;
        if (ls >= 0)
            acc = fmaf(xr[((size_t)(bl - (DC - 1) + k)) * (2 * DI) + d], wp[k], acc);
    }
    xs[idx] = acc / (1.f + __expf(-acc));          // silu
}

// ---------------------------------------------------------------------------
// f32 -> bf16 flat convert (weights)
__global__ __launch_bounds__(256) void f2bf_k(const float* __restrict__ in,
    unsigned short* __restrict__ out, int n)
{
    int i = blockIdx.x * 256 + threadIdx.x;
    if (i < n) out[i] = f2bf(in[i]);
}

// ---------------------------------------------------------------------------
// xdbl C columns [TOK][XD] -> CT [BB*DS][WLEN]
__global__ __launch_bounds__(256) void trans_CT_k(const float* __restrict__ xdbl,
    float* __restrict__ CT)
{
    __shared__ float tile[64][65];
    int bt = blockIdx.x, b = blockIdx.z;
    int col = threadIdx.x & 63, rr = threadIdx.x >> 6;
#pragma unroll
    for (int k = 0; k < 16; k++) {
        int i = k * 4 + rr;
        tile[i][col] = xdbl[((size_t)(b * WLEN + bt * 64 + i)) * XD + DR + DS + col];
    }
    __syncthreads();
#pragma unroll
    for (int k = 0; k < 16; k++) {
        int ss = k * 4 + rr;
        CT[((size_t)(b * DS + ss)) * WLEN + bt * 64 + col] = tile[col][ss];
    }
}

// yT [BB*DI][WLEN] f32 -> y_bf [TOK][DI] bf16
__global__ __launch_bounds__(256) void trans_y_k(const float* __restrict__ yT,
    unsigned short* __restrict__ ybf)
{
    __shared__ float tile[64][65];
    int bt = blockIdx.x, bd = blockIdx.y, b = blockIdx.z;
    int col = threadIdx.x & 63, rr = threadIdx.x >> 6;
#pragma unroll
    for (int k = 0; k < 16; k++) {
        int i = k * 4 + rr;   // d index
        tile[i][col] = yT[((size_t)(b * DI + bd * 64 + i)) * WLEN + bt * 64 + col];
    }
    __syncthreads();
#pragma unroll
    for (int k = 0; k < 16; k++) {
        int tt = k * 4 + rr;  // t index
        ybf[((size_t)(b * WLEN + bt * 64 + tt)) * DI + bd * 64 + col] = f2bf(tile[col][tt]);
    }
}

// ---------------------------------------------------------------------------
// Chunked selective scan.
#define SU 8

#define LOADG1(T0, dlt, xv, Bt, Ct)                                      \
  _Pragma("unroll")                                                      \
  for (int u = 0; u < SU; u++) {                                         \
    size_t bl = base + (size_t)(T0) + u;                                 \
    dlt[u] = delta[bl * DI + d];                                         \
    xv[u]  = xs[bl * DI + d];                                            \
    Bt[u]  = xdbl[bl * XD + DR + lane];                                  \
    Ct[u]  = xdbl[bl * XD + DR + DS + lane];                             \
  }

// LDS-transpose reduction: p[u] written to wred[u][lane]; each lane then
// sums 8 contiguous floats of row (lane>>3); 3 shfl stages finish the 64-sum.
#define COMPG1(T0, dlt, xv, Bt, Ct)                                      \
  {                                                                      \
    float dA[SU], p[SU], cds[SU];                                        \
    _Pragma("unroll")                                                    \
    for (int u = 0; u < SU; u++) dA[u] = __expf(dlt[u] * Aa);            \
    _Pragma("unroll")                                                    \
    for (int u = 0; u < SU; u++) {                                       \
      hst = fmaf(dA[u], hst, dlt[u] * xv[u] * Bt[u]);                    \
      p[u] = hst * Ct[u];                                                \
    }                                                                    \
    if (lane == 0) {                                                     \
      _Pragma("unroll")                                                  \
      for (int u = 0; u < SU; u++) p[u] = fmaf(xv[u], Dpd, p[u]);        \
    }                                                                    \
    cds[0] = cd + dlt[0];                                                \
    _Pragma("unroll")                                                    \
    for (int u = 1; u < SU; u++) cds[u] = cds[u - 1] + dlt[u];           \
    cd = cds[SU - 1];                                                    \
    _Pragma("unroll")                                                    \
    for (int u = 0; u < SU; u++)                                         \
      if (lane == u) cdT[tbase + (size_t)(T0) + u] = cds[u];             \
    _Pragma("unroll")                                                    \
    for (int u = 0; u < SU; u++) wred[u * 64 + lane] = p[u];             \
    float4 q0 = *(const float4*)&wred[(lane >> 3) * 64 + (lane & 7) * 8];     \
    float4 q1 = *(const float4*)&wred[(lane >> 3) * 64 + (lane & 7) * 8 + 4]; \
    float sred = ((q0.x + q0.y) + (q0.z + q0.w)) +                       \
                 ((q1.x + q1.y) + (q1.z + q1.w));                        \
    sred += __shfl_xor(sred, 1, 64);                                     \
    sred += __shfl_xor(sred, 2, 64);                                     \
    sred += __shfl_xor(sred, 4, 64);                                     \
    if ((lane & 7) == 0) zT[tbase + (size_t)(T0) + (lane >> 3)] = sred;  \
  }

__global__ __launch_bounds__(256) void scan1_k(
    const float* __restrict__ delta,    // [TOK][DI]
    const float* __restrict__ xdbl,     // [TOK][XD]
    const float* __restrict__ xs,       // [TOK][DI]
    const float* __restrict__ A_log,    // [DI][DS]
    const float* __restrict__ Dp,       // [DI]
    float* __restrict__ zT,             // [BB*DI][WLEN]  z = y_loc + xs*Dp
    float* __restrict__ cdT,            // [BB*DI][WLEN]  inclusive delta prefix
    float* __restrict__ Hbuf,           // [2048*NCH][DS]
    float* __restrict__ Sbuf)           // [2048*NCH]
{
    __shared__ float red[4 * SU * 64];
    int wv   = threadIdx.x >> 6;
    float* wred = red + wv * (SU * 64);
    int wid  = blockIdx.x * 4 + wv;     // 0..32767 == bd*NCH+c
    int lane = threadIdx.x & 63;
    int c  = wid & (NCH - 1);
    int bd = wid >> 4;                  // b*DI + d
    int d  = bd & (DI - 1);
    float Aa  = -__expf(A_log[d * DS + lane]);
    float Dpd = Dp[d];
    float hst = 0.f, cd = 0.f;
    size_t base  = (size_t)(bd >> 10) * WLEN + (size_t)c * CL;  // global token base
    size_t tbase = (size_t)bd * WLEN + (size_t)c * CL;          // transposed-plane base

    float da[SU], xa[SU], Ba[SU], Ca[SU];
    float db[SU], xb[SU], Bb[SU], Cb[SU];

    LOADG1(0, da, xa, Ba, Ca)
    for (int t0 = 0; t0 < CL; t0 += 2 * SU) {
        LOADG1(t0 + SU, db, xb, Bb, Cb)
        COMPG1(t0, da, xa, Ba, Ca)
        if (t0 + 2 * SU < CL)
            LOADG1(t0 + 2 * SU, da, xa, Ba, Ca)
        COMPG1(t0 + SU, db, xb, Bb, Cb)
    }
    Hbuf[(size_t)wid * DS + lane] = hst;
    if (lane == 0) Sbuf[wid] = cd;
}

__global__ __launch_bounds__(256) void scan2_k(
    const float* __restrict__ Hbuf, const float* __restrict__ Sbuf,
    const float* __restrict__ A_log, float* __restrict__ h0buf)
{
    int bd   = blockIdx.x * 4 + (threadIdx.x >> 6);  // 0..2047
    int lane = threadIdx.x & 63;
    int d = bd & (DI - 1);
    float Aa = -__expf(A_log[d * DS + lane]);
    float h = 0.f;
#pragma unroll
    for (int c = 0; c < NCH; c++) {
        size_t i = (size_t)bd * NCH + c;
        h0buf[i * DS + lane] = h;
        h = __expf(Aa * Sbuf[i]) * h + Hbuf[i * DS + lane];
    }
}

// scan3: lane = token. corr_t = sum_s C[t,s]*exp2(K_s*cd_t)*h0_s, then gate.
static __device__ __forceinline__ float lanef(float v, int s) {
    return __uint_as_float(__builtin_amdgcn_readlane(__float_as_uint(v), s));
}

__global__ __launch_bounds__(256) void scan3_k(
    const float* __restrict__ zT,
    const float* __restrict__ cdT,
    const float* __restrict__ rT,
    const float* __restrict__ CT,       // [BB*DS][WLEN]
    const float* __restrict__ A_log,
    const float* __restrict__ h0buf,
    float* __restrict__ yT)             // [BB*DI][WLEN]
{
    int wid  = blockIdx.x * 4 + (threadIdx.x >> 6);  // bd*NCH + c
    int lane = threadIdx.x & 63;
    int c  = wid & (NCH - 1);
    int bd = wid >> 4;
    int d  = bd & (DI - 1);
    int b  = bd >> 10;
    float Kv  = -__expf(A_log[d * DS + lane]) * LOG2E;   // lane as s
    float h0v = h0buf[(size_t)wid * DS + lane];          // lane as s
    size_t rowb = (size_t)bd * WLEN;
    const float* CTb = CT + (size_t)b * DS * WLEN;

#pragma unroll
    for (int pass = 0; pass < CL / 64; pass++) {
        int t = c * CL + pass * 64 + lane;
        float cd = cdT[rowb + t];
        float z  = zT[rowb + t];
        float r  = rT[rowb + t];
        float c0 = 0.f, c1 = 0.f, c2 = 0.f, c3 = 0.f;
#pragma unroll
        for (int s = 0; s < DS; s += 4) {
            float C0 = CTb[(size_t)(s + 0) * WLEN + t];
            float C1 = CTb[(size_t)(s + 1) * WLEN + t];
            float C2 = CTb[(size_t)(s + 2) * WLEN + t];
            float C3 = CTb[(size_t)(s + 3) * WLEN + t];
            c0 = fmaf(C0 * lanef(h0v, s + 0), exp2f(lanef(Kv, s + 0) * cd), c0);
            c1 = fmaf(C1 * lanef(h0v, s + 1), exp2f(lanef(Kv, s + 1) * cd), c1);
            c2 = fmaf(C2 * lanef(h0v, s + 2), exp2f(lanef(Kv, s + 2) * cd), c2);
            c3 = fmaf(C3 * lanef(h0v, s + 3), exp2f(lanef(Kv, s + 3) * cd), c3);
        }
        float corr = (c0 + c1) + (c2 + c3);
        float yv = (z + corr) * (r / (1.f + __expf(-r)));
        yT[rowb + t] = yv;
    }
}

// ---------------------------------------------------------------------------
// bf16 MFMA NT GEMM: C[M][N] = A[M][K] * W[N][K]^T, f32 out.
// 128x128 tile, BK=32, 4 waves (2x2 of 64x64), mfma_f32_16x16x32_bf16.
// EPI: 4 = +resid;  5 = m_in split: n<DI -> C (xr), n>=DI -> rT transposed
template<int EPI>
__global__ __launch_bounds__(256) void gemm_bf16(
    const unsigned short* __restrict__ A,   // [M][K] bf16
    const unsigned short* __restrict__ W,   // [N][K] bf16
    const float* __restrict__ resid,
    float* __restrict__ C,
    float* __restrict__ rT,
    int M, int N, int K)
{
    __shared__ unsigned short As[4 * 128 * 8];   // [kg][row][j]
    __shared__ unsigned short Bs[4 * 128 * 8];
    const int tid = threadIdx.x;
    const int bm = blockIdx.x * 128, bn = blockIdx.y * 128;
    const int l = tid & 63, w = tid >> 6;
    const int wm = (w >> 1) * 64, wn = (w & 1) * 64;
    const int srow = tid >> 1, shalf = tid & 1;
    const int kq = l >> 4, lr = l & 15;

    f32x4 acc[4][4];
#pragma unroll
    for (int i = 0; i < 4; i++)
#pragma unroll
        for (int j = 0; j < 4; j++)
            acc[i][j] = f32x4{0.f, 0.f, 0.f, 0.f};

    for (int k0 = 0; k0 < K; k0 += 32) {
        const uint4* ga = (const uint4*)(A + (size_t)(bm + srow) * K + k0 + shalf * 16);
        uint4 a0 = ga[0], a1 = ga[1];
        const uint4* gb = (const uint4*)(W + (size_t)(bn + srow) * K + k0 + shalf * 16);
        uint4 b0 = gb[0], b1 = gb[1];
        __syncthreads();
        int kg = shalf * 2;
        *(uint4*)&As[((kg    ) * 128 + srow) * 8] = a0;
        *(uint4*)&As[((kg + 1) * 128 + srow) * 8] = a1;
        *(uint4*)&Bs[((kg    ) * 128 + srow) * 8] = b0;
        *(uint4*)&Bs[((kg + 1) * 128 + srow) * 8] = b1;
        __syncthreads();
        bf16x8 av[4], bv[4];
#pragma unroll
        for (int mf = 0; mf < 4; mf++)
            av[mf] = *(const bf16x8*)&As[(kq * 128 + wm + mf * 16 + lr) * 8];
#pragma unroll
        for (int nf = 0; nf < 4; nf++)
            bv[nf] = *(const bf16x8*)&Bs[(kq * 128 + wn + nf * 16 + lr) * 8];
#pragma unroll
        for (int mf = 0; mf < 4; mf++)
#pragma unroll
            for (int nf = 0; nf < 4; nf++)
                acc[mf][nf] = __builtin_amdgcn_mfma_f32_16x16x32_bf16(
                    av[mf], bv[nf], acc[mf][nf], 0, 0, 0);
    }
#pragma unroll
    for (int mf = 0; mf < 4; mf++) {
#pragma unroll
        for (int nf = 0; nf < 4; nf++) {
            int n  = bn + wn + nf * 16 + lr;
            int m0 = bm + wm + mf * 16 + kq * 4;
            if (EPI == 5 && n >= DI) {
                float4 val = make_float4(acc[mf][nf][0], acc[mf][nf][1],
                                         acc[mf][nf][2], acc[mf][nf][3]);
                int b = m0 >> 11, ll = m0 & (WLEN - 1);
                *(float4*)&rT[((size_t)((b << 10) + (n - DI))) * WLEN + ll] = val;
            } else {
#pragma unroll
                for (int r = 0; r < 4; r++) {
                    int m = m0 + r;
                    float v = acc[mf][nf][r];
                    if (EPI == 4) v += resid[(size_t)m * N + n];
                    C[(size_t)m * N + n] = v;
                }
            }
        }
    }
}

// ---------------------------------------------------------------------------
// Generic f32 NT GEMM (small GEMMs): C = A*W^T (+ epilogue)
// EPI: 0 none, 1 +bias, 2 relu(+bias), 3 softplus(+bias)
template<int EPI>
__global__ __launch_bounds__(256) void gemm_nt(
    const float* __restrict__ A, int lda,
    const float* __restrict__ W, int ldw,
    const float* __restrict__ bias,
    float* __restrict__ C, int ldc,
    int M, int N, int K)
{
    __shared__ float As[16][64];
    __shared__ float Ws[16][64];
    const int tid = threadIdx.x;
    const int tx = tid & 15;
    const int ty = tid >> 4;
    const int bm = blockIdx.x * 64;
    const int bn = blockIdx.y * 64;
    const int lr = tid >> 2;
    const int lc = (tid & 3) << 2;
    float acc[4][4] = {};
    for (int k0 = 0; k0 < K; k0 += 16) {
        float4 av = *(const float4*)(A + (size_t)(bm + lr) * lda + (k0 + lc));
        float4 wv = make_float4(0.f, 0.f, 0.f, 0.f);
        if (bn + lr < N)
            wv = *(const float4*)(W + (size_t)(bn + lr) * ldw + (k0 + lc));
        As[lc + 0][lr] = av.x; As[lc + 1][lr] = av.y;
        As[lc + 2][lr] = av.z; As[lc + 3][lr] = av.w;
        Ws[lc + 0][lr] = wv.x; Ws[lc + 1][lr] = wv.y;
        Ws[lc + 2][lr] = wv.z; Ws[lc + 3][lr] = wv.w;
        __syncthreads();
#pragma unroll
        for (int k = 0; k < 16; ++k) {
            float4 a = *(const float4*)&As[k][ty * 4];
            float4 w = *(const float4*)&Ws[k][tx * 4];
            float aa[4] = {a.x, a.y, a.z, a.w};
            float ww[4] = {w.x, w.y, w.z, w.w};
#pragma unroll
            for (int i = 0; i < 4; i++)
#pragma unroll
                for (int j = 0; j < 4; j++)
                    acc[i][j] = fmaf(aa[i], ww[j], acc[i][j]);
        }
        __syncthreads();
    }
#pragma unroll
    for (int i = 0; i < 4; i++) {
        int m = bm + ty * 4 + i;
#pragma unroll
        for (int j = 0; j < 4; j++) {
            int n = bn + tx * 4 + j;
            if (n >= N) continue;
            float v = acc[i][j];
            if (EPI == 1 || EPI == 2 || EPI == 3) v += bias[n];
            if (EPI == 2) v = fmaxf(v, 0.f);
            if (EPI == 3) v = fmaxf(v, 0.f) + log1pf(__expf(-fabsf(v)));
            C[(size_t)m * ldc + n] = v;
        }
    }
}

// ---------------------------------------------------------------------------
extern "C" void kernel_launch(void* const* d_in, const int* in_sizes, int n_in,
                              void* d_out, int out_size, void* d_ws, size_t ws_size,
                              hipStream_t stream)
{
    const int*   seq        = (const int*)d_in[0];
    const float* byte_embed = (const float*)d_in[1];
    const float* pos_embed  = (const float*)d_in[2];
    const float* in_w       = (const float*)d_in[3];
    const float* in_b       = (const float*)d_in[4];
    const float* ln_g       = (const float*)d_in[5];
    const float* ln_b       = (const float*)d_in[6];
    const float* m_in_w     = (const float*)d_in[7];
    const float* conv_w     = (const float*)d_in[8];
    const float* conv_b     = (const float*)d_in[9];
    const float* xp_w       = (const float*)d_in[10];
    const float* dt_w       = (const float*)d_in[11];
    const float* dt_b       = (const float*)d_in[12];
    const float* A_log      = (const float*)d_in[13];
    const float* Dp         = (const float*)d_in[14];
    const float* m_out_w    = (const float*)d_in[15];
    const float* h1_w       = (const float*)d_in[16];
    const float* h1_b       = (const float*)d_in[17];
    const float* h2_w       = (const float*)d_in[18];
    const float* h2_b       = (const float*)d_in[19];
    const float* h3_w       = (const float*)d_in[20];
    const float* h3_b       = (const float*)d_in[21];
    float* out = (float*)d_out;

    float* ws = (float*)d_ws;
    size_t off = 0;
    float* xe    = ws + off; off += (size_t)TOK * EDIM;        // 4 MB
    float* x     = ws + off; off += (size_t)TOK * DDIM;        // residual stream
    float* xr    = ws + off; off += (size_t)TOK * 2 * DI;      // 32 MB
    float* xs    = ws + off; off += (size_t)TOK * DI;          // 16 MB
    float* xdbl  = ws + off; off += (size_t)TOK * XD;
    float* delta = ws + off; off += (size_t)TOK * DI;          // also yT (aliased)
    float* zT    = ws + off; off += (size_t)BB * DI * WLEN;
    float* cdT   = ws + off; off += (size_t)BB * DI * WLEN;
    float* rT    = ws + off; off += (size_t)BB * DI * WLEN;
    float* CT    = ws + off; off += (size_t)BB * DS * WLEN;
    float* Hbuf  = ws + off; off += (size_t)BB * DI * NCH * DS;
    float* h0buf = ws + off; off += (size_t)BB * DI * NCH * DS;
    float* Sbuf  = ws + off; off += (size_t)BB * DI * NCH;
    unsigned short* h_bf  = (unsigned short*)(ws + off); off += (size_t)TOK * DDIM / 2;
    unsigned short* y_bf  = (unsigned short*)(ws + off); off += (size_t)TOK * DI / 2;
    unsigned short* wmi_bf = (unsigned short*)(ws + off); off += (size_t)NLAYER * 2 * DI * DDIM / 2;
    unsigned short* wmo_bf = (unsigned short*)(ws + off); off += (size_t)NLAYER * DDIM * DI / 2;
    float* yT = delta;            // scan3 output aliases delta (dead after scan1)
    float* t1 = xe;               // head temps
    float* t2 = (float*)h_bf;

    // Weight conversions (every call; harness re-poisons ws)
    {
        int n1 = NLAYER * 2 * DI * DDIM;
        f2bf_k<<<(n1 + 255) / 256, 256, 0, stream>>>(m_in_w, wmi_bf, n1);
        int n2 = NLAYER * DDIM * DI;
        f2bf_k<<<(n2 + 255) / 256, 256, 0, stream>>>(m_out_w, wmo_bf, n2);
    }

    // Embed + input projection (f32)
    embed_k<<<TOK * EDIM / 256, 256, 0, stream>>>(seq, byte_embed, pos_embed, xe);
    gemm_nt<1><<<dim3(TOK/64, DDIM/64), 256, 0, stream>>>(
        xe, EDIM, in_w, EDIM, in_b, x, DDIM, TOK, DDIM, EDIM);

    for (int i = 0; i < NLAYER; i++) {
        const float* lg  = ln_g  + (size_t)i * DDIM;
        const float* lb  = ln_b  + (size_t)i * DDIM;
        const unsigned short* miw = wmi_bf + (size_t)i * 2 * DI * DDIM;
        const float* cw  = conv_w + (size_t)i * DI * DC;
        const float* cb  = conv_b + (size_t)i * DI;
        const float* xpw = xp_w  + (size_t)i * XD * DI;
        const float* dtw = dt_w  + (size_t)i * DI * DR;
        const float* dtb = dt_b  + (size_t)i * DI;
        const float* al  = A_log + (size_t)i * DI * DS;
        const float* dp  = Dp    + (size_t)i * DI;
        const unsigned short* mow = wmo_bf + (size_t)i * DDIM * DI;

        ln_k<<<TOK/4, 256, 0, stream>>>(x, lg, lb, h_bf);
        // m_in GEMM with fused transposed write of the residual half -> rT
        gemm_bf16<5><<<dim3(TOK/128, 2*DI/128), 256, 0, stream>>>(
            h_bf, miw, nullptr, xr, rT, TOK, 2*DI, DDIM);
        conv_silu_k<<<TOK * DI / 256, 256, 0, stream>>>(xr, cw, cb, xs);
        gemm_nt<0><<<dim3(TOK/64, (XD+63)/64), 256, 0, stream>>>(
            xs, DI, xpw, DI, nullptr, xdbl, XD, TOK, XD, DI);
        trans_CT_k<<<dim3(WLEN/64, 1, BB), 256, 0, stream>>>(xdbl, CT);
        gemm_nt<3><<<dim3(TOK/64, DI/64), 256, 0, stream>>>(
            xdbl, XD, dtw, DR, dtb, delta, DI, TOK, DI, DR);

        scan1_k<<<(BB*DI*NCH)/4, 256, 0, stream>>>(
            delta, xdbl, xs, al, dp, zT, cdT, Hbuf, Sbuf);
        scan2_k<<<(BB*DI)/4, 256, 0, stream>>>(Hbuf, Sbuf, al, h0buf);
        scan3_k<<<(BB*DI*NCH)/4, 256, 0, stream>>>(
            zT, cdT, rT, CT, al, h0buf, yT);
        trans_y_k<<<dim3(WLEN/64, DI/64, BB), 256, 0, stream>>>(yT, y_bf);

        gemm_bf16<4><<<dim3(TOK/128, DDIM/128), 256, 0, stream>>>(
            y_bf, mow, x, x, nullptr, TOK, DDIM, DI);
    }

    // Head (f32)
    gemm_nt<2><<<dim3(TOK/64, 256/64), 256, 0, stream>>>(
        x, DDIM, h1_w, DDIM, h1_b, t1, 256, TOK, 256, DDIM);
    gemm_nt<2><<<dim3(TOK/64, 2), 256, 0, stream>>>(
        t1, 256, h2_w, 256, h2_b, t2, 128, TOK, 128, 256);
    gemm_nt<1><<<dim3(TOK/64, 1), 256, 0, stream>>>(
        t2, 128, h3_w, 128, h3_b, out, NCLS, TOK, NCLS, 128);
}